// Round 8
// baseline (25.779 us; speedup 1.0000x reference)
//
#include <hip/hip_runtime.h>
#include <math.h>

#define NUM_ENTITY 100000
#define NUM_TYPE   5000
#define DIM        128
#define BATCH      512
#define MARGIN     2.0f

#define BT 32            // batch-tile rows per block
#define TT 32            // type-tile cols per block
#define HSTRIDE 136      // staged row stride in HALVES (68 dw ≡ 4 mod 32 banks)
#define PSTRIDE 68       // reduce-area row stride in floats (64 + 4 pad)

typedef _Float16 half_t;
typedef half_t half2_t __attribute__((ext_vector_type(2)));
typedef half_t half4_t __attribute__((ext_vector_type(4)));

// r7 at 25.8us vs ~8us issue floor with 10048-wave supply -> SIMDs issuing
// ~32% of cycles. Suspect: full unroll of the ks-loop let the scheduler hoist
// all 32 ds_read_b128 (128 operand VGPRs) -> ~200 VGPR -> 2 waves/SIMD ->
// 2 blocks/CU -> barrier convoys. This round: __launch_bounds__(256,2)
// (128-VGPR cap = 4 blocks/CU) + '#pragma unroll 2' on ks (only 2 k-steps'
// operands live ~64 VGPR; live-set ~110 < cap, so no spill — r1/r2's spills
// came from caps BELOW the live-set). Everything else identical to r7.
__global__ __launch_bounds__(256, 2) void l1dist_sigmoid_kernel(
    const float* __restrict__ ent,
    const float* __restrict__ typ,
    const int*   __restrict__ xb,
    float*       __restrict__ out)
{
    // staging area (f16): 2 tiles * 32 rows * 136 halves * 2B = 17408 B
    // reduce overlay (f32): 64 lanes * 68 floats * 4B = 17408 B (exact reuse)
    __shared__ float smem[2 * BT * HSTRIDE / 2];
    half_t* eH = (half_t*)smem;                    // [32][HSTRIDE]
    half_t* tH = (half_t*)smem + BT * HSTRIDE;     // [32][HSTRIDE]

    const int tid = threadIdx.x;    // 0..255
    const int l   = tid & 63;       // lane in wave
    const int w   = tid >> 6;       // wave 0..3
    const int tx  = l & 7;          // type-dir thread coord (8)
    const int ty  = l >> 3;         // batch-dir thread coord (8)
    const int b0  = blockIdx.y * BT;
    const int t0  = blockIdx.x * TT;

    // ---- stage full 128-dim tiles as f16: g = tid+256s -> row g>>5, c4 = g&31
#pragma unroll
    for (int s = 0; s < 4; ++s) {
        const int g = tid + 256 * s;
        const int row = g >> 5, c4 = g & 31;
        const int er = xb[b0 + row];
        const float4 v = *(const float4*)&ent[er * DIM + c4 * 4];
        half4_t hv = {(half_t)v.x, (half_t)v.y, (half_t)v.z, (half_t)v.w};
        *(half4_t*)&eH[row * HSTRIDE + c4 * 4] = hv;
    }
#pragma unroll
    for (int s = 0; s < 4; ++s) {
        const int g = tid + 256 * s;
        const int row = g >> 5, c4 = g & 31;
        const int tr = min(t0 + row, NUM_TYPE - 1);
        const float4 v = *(const float4*)&typ[tr * DIM + c4 * 4];
        half4_t hv = {(half_t)v.x, (half_t)v.y, (half_t)v.z, (half_t)v.w};
        *(half4_t*)&tH[row * HSTRIDE + c4 * 4] = hv;
    }
    __syncthreads();

    // ---- compute: wave w covers dims [32w, 32w+32); 4 k-steps of 8 dims
    const half2_t ones = {(half_t)1.0f, (half_t)1.0f};
    float acc[4][4] = {};
    const int kbase = w * 32;

#if __has_builtin(__builtin_amdgcn_fdot2)
#define ABS_DOT2(EU, TU, ACC)                                                  \
    {                                                                          \
        half2_t _d = __builtin_bit_cast(half2_t, (EU)) -                       \
                     __builtin_bit_cast(half2_t, (TU));                        \
        unsigned _du = __builtin_bit_cast(unsigned, _d) & 0x7fff7fffu;         \
        ACC = __builtin_amdgcn_fdot2(__builtin_bit_cast(half2_t, _du), ones,   \
                                     ACC, false);                              \
    }
#else
#define ABS_DOT2(EU, TU, ACC)                                                  \
    {                                                                          \
        half2_t _d = __builtin_bit_cast(half2_t, (EU)) -                       \
                     __builtin_bit_cast(half2_t, (TU));                        \
        unsigned _du = __builtin_bit_cast(unsigned, _d) & 0x7fff7fffu;         \
        half2_t _a = __builtin_bit_cast(half2_t, _du);                         \
        ACC += (float)_a[0] + (float)_a[1];                                    \
    }
#endif

    // unroll 2: only two k-steps' operands (64 VGPR) live at once — caps the
    // scheduler's ds_read hoisting that blew the register budget in r7.
#pragma unroll 2
    for (int ks = 0; ks < 4; ++ks) {
        const int kk = kbase + 8 * ks;
        uint4 ev[4], tv[4];   // 8 halves each (16 B)
#pragma unroll
        for (int i = 0; i < 4; ++i)
            ev[i] = *(const uint4*)&eH[(ty + 8 * i) * HSTRIDE + kk];
#pragma unroll
        for (int j = 0; j < 4; ++j)
            tv[j] = *(const uint4*)&tH[(tx + 8 * j) * HSTRIDE + kk];
#pragma unroll
        for (int i = 0; i < 4; ++i)
#pragma unroll
            for (int j = 0; j < 4; ++j) {
                ABS_DOT2(ev[i].x, tv[j].x, acc[i][j])
                ABS_DOT2(ev[i].y, tv[j].y, acc[i][j])
                ABS_DOT2(ev[i].z, tv[j].z, acc[i][j])
                ABS_DOT2(ev[i].w, tv[j].w, acc[i][j])
            }
    }
    __syncthreads();   // all waves done reading eH/tH; safe to overlay

    // ---- cross-wave reduction: part[l][w*16 + i*4 + j], row stride PSTRIDE
    float* part = smem;
#pragma unroll
    for (int i = 0; i < 4; ++i) {
        float4 v;
        v.x = acc[i][0]; v.y = acc[i][1]; v.z = acc[i][2]; v.w = acc[i][3];
        *(float4*)&part[l * PSTRIDE + w * 16 + i * 4] = v;
    }
    __syncthreads();

    // ---- final: thread (w,l) owns outputs (i=w, j=0..3) of lane l
    float4 sum;
    sum.x = 0.0f; sum.y = 0.0f; sum.z = 0.0f; sum.w = 0.0f;
#pragma unroll
    for (int wp = 0; wp < 4; ++wp) {
        const float4 v = *(const float4*)&part[l * PSTRIDE + wp * 16 + w * 4];
        sum.x += v.x; sum.y += v.y; sum.z += v.z; sum.w += v.w;
    }

    const int b = b0 + ty + 8 * w;
    const float d[4] = {sum.x, sum.y, sum.z, sum.w};
#pragma unroll
    for (int j = 0; j < 4; ++j) {
        const int t = t0 + tx + 8 * j;
        if (t < NUM_TYPE) {
            const float x = MARGIN - d[j];
            out[b * NUM_TYPE + t] = 1.0f / (1.0f + __expf(-x));
        }
    }
}

extern "C" void kernel_launch(void* const* d_in, const int* in_sizes, int n_in,
                              void* d_out, int out_size, void* d_ws, size_t ws_size,
                              hipStream_t stream) {
    const float* ent = (const float*)d_in[0];
    const float* typ = (const float*)d_in[1];
    const int*   xb  = (const int*)d_in[2];
    float*       out = (float*)d_out;

    dim3 grid((NUM_TYPE + TT - 1) / TT, BATCH / BT);  // (157, 16) = 2512 blocks x 4 waves
    dim3 block(256);
    l1dist_sigmoid_kernel<<<grid, block, 0, stream>>>(ent, typ, xb, out);
}